// Round 1
// baseline (1386.300 us; speedup 1.0000x reference)
//
#include <hip/hip_runtime.h>
#include <cmath>

// ---- problem constants ----
constexpr int Bn = 64;
constexpr int TKn = 2048;
constexpr int Hn = 512;
constexpr int En = 128;
constexpr int Vn = 50000;
constexpr int NOOVn = 512;
constexpr int VXn = Vn + NOOVn;   // 50512

// ---- d_out layout (float offsets), flat tuple order ----
constexpr size_t OFF_FINAL = 0;                              // B x VX
constexpr size_t OFF_H     = (size_t)Bn * VXn;               // B x H
constexpr size_t OFF_C     = OFF_H + (size_t)Bn * Hn;        // B x H
constexpr size_t OFF_CT    = OFF_C + (size_t)Bn * Hn;        // B x 2H
constexpr size_t OFF_ATTN  = OFF_CT + (size_t)Bn * 2 * Hn;   // B x TK
constexpr size_t OFF_PGEN  = OFF_ATTN + (size_t)Bn * TKn;    // B
constexpr size_t OFF_COV   = OFF_PGEN + Bn;                  // B x TK

// ---- workspace layout (float offsets) ----
constexpr size_t WS_X      = 0;                               // B x E
constexpr size_t WS_DECF   = WS_X + (size_t)Bn * En;          // B x 2H
constexpr size_t WS_SCORES = WS_DECF + (size_t)Bn * 2 * Hn;   // B x TK
constexpr size_t WS_OUT1   = WS_SCORES + (size_t)Bn * TKn;    // B x H
constexpr size_t WS_VMAX   = WS_OUT1 + (size_t)Bn * Hn;       // B
constexpr size_t WS_VSUM   = WS_VMAX + Bn;                    // B

__device__ __forceinline__ float wave_sum(float v) {
#pragma unroll
    for (int o = 32; o; o >>= 1) v += __shfl_xor(v, o, 64);
    return v;
}

__device__ __forceinline__ float sigm(float x) { return 1.f / (1.f + expf(-x)); }

// K1: x[b][e] = concat(c_t_1, emb) @ W_ctx.T + b_ctx   (one wave per output elem)
__global__ void k_ctx(const int* __restrict__ ids, const float* __restrict__ ct1,
                      const float* __restrict__ Wemb, const float* __restrict__ Wctx,
                      const float* __restrict__ bctx, float* __restrict__ xout) {
    int w = (blockIdx.x * 256 + threadIdx.x) >> 6;   // 0..8191
    int lane = threadIdx.x & 63;
    int b = w >> 7, e = w & 127;
    const float* wr = Wctx + (size_t)e * 1152;
    int row = ids[b];
    float acc = 0.f;
    for (int k = lane; k < 1152; k += 64) {
        float xv = (k < 1024) ? ct1[b * 1024 + k] : Wemb[(size_t)row * 128 + (k - 1024)];
        acc += xv * wr[k];
    }
    acc = wave_sum(acc);
    if (lane == 0) xout[b * 128 + e] = acc + bctx[e];
}

// K2: LSTM step -> h_dec, c_dec written straight to d_out (one wave per (b,j))
__global__ void k_lstm(const float* __restrict__ x, const float* __restrict__ h0,
                       const float* __restrict__ c0, const float* __restrict__ Wih,
                       const float* __restrict__ Whh, const float* __restrict__ bih,
                       const float* __restrict__ bhh, float* __restrict__ out) {
    int w = (blockIdx.x * 256 + threadIdx.x) >> 6;   // 0..32767
    int lane = threadIdx.x & 63;
    int b = w >> 9, j = w & 511;
    const float* xr = x + b * 128;
    const float* hr = h0 + b * 512;
    float ai = 0.f, af = 0.f, ag = 0.f, ao = 0.f;
    for (int k = lane; k < 128; k += 64) {
        float xv = xr[k];
        ai += xv * Wih[(size_t)(j       ) * 128 + k];
        af += xv * Wih[(size_t)(j +  512) * 128 + k];
        ag += xv * Wih[(size_t)(j + 1024) * 128 + k];
        ao += xv * Wih[(size_t)(j + 1536) * 128 + k];
    }
    for (int k = lane; k < 512; k += 64) {
        float hv = hr[k];
        ai += hv * Whh[(size_t)(j       ) * 512 + k];
        af += hv * Whh[(size_t)(j +  512) * 512 + k];
        ag += hv * Whh[(size_t)(j + 1024) * 512 + k];
        ao += hv * Whh[(size_t)(j + 1536) * 512 + k];
    }
    ai = wave_sum(ai); af = wave_sum(af); ag = wave_sum(ag); ao = wave_sum(ao);
    if (lane == 0) {
        ai += bih[j       ] + bhh[j       ];
        af += bih[j +  512] + bhh[j +  512];
        ag += bih[j + 1024] + bhh[j + 1024];
        ao += bih[j + 1536] + bhh[j + 1536];
        float c = sigm(af) * c0[b * 512 + j] + sigm(ai) * tanhf(ag);
        float h = sigm(ao) * tanhf(c);
        out[OFF_H + b * 512 + j] = h;
        out[OFF_C + b * 512 + j] = c;
    }
}

// K3: dec_feature[b][n] = [h,c] @ W_attn.T + b_attn (one wave per output elem)
__global__ void k_decfeat(const float* __restrict__ out, const float* __restrict__ Wattn,
                          const float* __restrict__ battn, float* __restrict__ decF) {
    int w = (blockIdx.x * 256 + threadIdx.x) >> 6;   // 0..65535
    int lane = threadIdx.x & 63;
    int b = w >> 10, n = w & 1023;
    const float* wr = Wattn + (size_t)n * 1024;
    float acc = 0.f;
    for (int m = lane; m < 512; m += 64) acc += out[OFF_H + b * 512 + m] * wr[m];
    for (int m = lane; m < 512; m += 64) acc += out[OFF_C + b * 512 + m] * wr[512 + m];
    acc = wave_sum(acc);
    if (lane == 0) decF[b * 1024 + n] = acc + battn[n];
}

// K4: scores[b][t] = sum_n tanh(encF[b,t,n] + decF[b,n]) * v_attn[n]  (one wave per (b,t))
__global__ void k_scores(const float4* __restrict__ encF, const float4* __restrict__ decF,
                         const float4* __restrict__ vat, float* __restrict__ scores) {
    int w = (blockIdx.x * 256 + threadIdx.x) >> 6;   // 0..131071
    int lane = threadIdx.x & 63;
    int b = w >> 11, t = w & 2047;
    size_t base = ((size_t)(b * TKn + t)) * 256;     // float4 units
    float acc = 0.f;
    for (int i = lane; i < 256; i += 64) {
        float4 f = encF[base + i];
        float4 d = decF[b * 256 + i];
        float4 vv = vat[i];
        acc += tanhf(f.x + d.x) * vv.x + tanhf(f.y + d.y) * vv.y +
               tanhf(f.z + d.z) * vv.z + tanhf(f.w + d.w) * vv.w;
    }
    acc = wave_sum(acc);
    if (lane == 0) scores[b * TKn + t] = acc;
}

// K5: attention softmax (masked + renorm) -> d_out; also copy coverage, zero c_t region
__global__ void k_attnsm(const float* __restrict__ scores, const float* __restrict__ mask,
                         const float* __restrict__ cov_in, float* __restrict__ out) {
    int b = blockIdx.x, tid = threadIdx.x;
    __shared__ float red[256];
    const float* sr = scores + b * TKn;

    float m = -1e30f;
    for (int t = tid; t < TKn; t += 256) m = fmaxf(m, sr[t]);
    red[tid] = m; __syncthreads();
    for (int s = 128; s > 0; s >>= 1) { if (tid < s) red[tid] = fmaxf(red[tid], red[tid + s]); __syncthreads(); }
    m = red[0]; __syncthreads();

    float s1 = 0.f;
    for (int t = tid; t < TKn; t += 256) s1 += expf(sr[t] - m);
    red[tid] = s1; __syncthreads();
    for (int s = 128; s > 0; s >>= 1) { if (tid < s) red[tid] += red[tid + s]; __syncthreads(); }
    s1 = red[0]; __syncthreads();
    float inv = 1.f / s1;

    float s2 = 0.f;
    for (int t = tid; t < TKn; t += 256) s2 += expf(sr[t] - m) * inv * mask[b * TKn + t];
    red[tid] = s2; __syncthreads();
    for (int s = 128; s > 0; s >>= 1) { if (tid < s) red[tid] += red[tid + s]; __syncthreads(); }
    s2 = red[0];
    float invd = 1.f / s2;

    for (int t = tid; t < TKn; t += 256) {
        out[OFF_ATTN + b * TKn + t] = expf(sr[t] - m) * inv * mask[b * TKn + t] * invd;
        out[OFF_COV  + b * TKn + t] = cov_in[b * TKn + t];
    }
    for (int n = tid; n < 1024; n += 256) out[OFF_CT + b * 1024 + n] = 0.f;
}

// K6: c_t[b][n] = sum_t attn[b][t] * encO[b][t][n]; block per (b, 128-t chunk), atomic finish
__global__ void k_ct(const float4* __restrict__ encO, float* __restrict__ out) {
    int b = blockIdx.x >> 4, ch = blockIdx.x & 15, tid = threadIdx.x;
    const float* ar = out + OFF_ATTN + b * TKn + ch * 128;
    float4 acc = {0.f, 0.f, 0.f, 0.f};
    size_t base = ((size_t)b * TKn + ch * 128) * 256 + tid;
    for (int tt = 0; tt < 128; tt++) {
        float a = ar[tt];
        float4 v = encO[base + (size_t)tt * 256];
        acc.x += a * v.x; acc.y += a * v.y; acc.z += a * v.z; acc.w += a * v.w;
    }
    float* ct = out + OFF_CT + b * 1024 + tid * 4;
    atomicAdd(ct + 0, acc.x); atomicAdd(ct + 1, acc.y);
    atomicAdd(ct + 2, acc.z); atomicAdd(ct + 3, acc.w);
}

// K7: p_gen[b] = sigmoid([c_t, h, c, x] @ W_pgen.T + b_pgen)   (one wave per b)
__global__ void k_pgen(const float* __restrict__ x, const float* __restrict__ Wp,
                       const float* __restrict__ bp, float* __restrict__ out) {
    int b = (blockIdx.x * 256 + threadIdx.x) >> 6;   // 0..63
    int lane = threadIdx.x & 63;
    float acc = 0.f;
    for (int k = lane; k < 2176; k += 64) {
        float v;
        if (k < 1024)       v = out[OFF_CT + b * 1024 + k];
        else if (k < 1536)  v = out[OFF_H + b * 512 + (k - 1024)];
        else if (k < 2048)  v = out[OFF_C + b * 512 + (k - 1536)];
        else                v = x[b * 128 + (k - 2048)];
        acc += v * Wp[k];
    }
    acc = wave_sum(acc);
    if (lane == 0) out[OFF_PGEN + b] = sigm(acc + bp[0]);
}

// K8: out1[b][j] = [h_dec, c_t] @ W_out1.T + b_out1   (one wave per output elem)
__global__ void k_out1(const float* __restrict__ out, const float* __restrict__ W1,
                       const float* __restrict__ b1, float* __restrict__ o1) {
    int w = (blockIdx.x * 256 + threadIdx.x) >> 6;   // 0..32767
    int lane = threadIdx.x & 63;
    int b = w >> 9, j = w & 511;
    const float* wr = W1 + (size_t)j * 1536;
    float acc = 0.f;
    for (int k = lane; k < 512; k += 64)  acc += out[OFF_H + b * 512 + k] * wr[k];
    for (int k = lane; k < 1024; k += 64) acc += out[OFF_CT + b * 1024 + k] * wr[512 + k];
    acc = wave_sum(acc);
    if (lane == 0) o1[b * 512 + j] = acc + b1[j];
}

// K9: logits[64][50000] = out1 @ W_out2.T + b_out2, written into final-output region
// (row stride VX). Register-tiled 64x64 tile, 4x4 micro, transposed LDS tiles.
__global__ __launch_bounds__(256) void k_gemm2(const float* __restrict__ o1,
                                               const float* __restrict__ W2,
                                               const float* __restrict__ b2,
                                               float* __restrict__ out) {
    __shared__ float As[64 * 68];   // As[k][b], row stride 68 (16B-aligned, bank-shifted)
    __shared__ float Ws[64 * 68];   // Ws[k][v]
    int tid = threadIdx.x;
    int v0 = blockIdx.x * 64;
    int tx = tid & 15, ty = tid >> 4;
    int lr = tid >> 2;   // loaded row 0..63
    int lq = tid & 3;    // k-slice quarter
    float acc[4][4] = {};

    for (int k0 = 0; k0 < 512; k0 += 64) {
        __syncthreads();
        // A tile (out1 rows = b), transpose into LDS
        const float4* arow = (const float4*)(o1 + (size_t)lr * 512 + k0 + lq * 16);
#pragma unroll
        for (int j = 0; j < 4; j++) {
            float4 v = arow[j];
            int kk = lq * 16 + j * 4;
            As[(kk + 0) * 68 + lr] = v.x;
            As[(kk + 1) * 68 + lr] = v.y;
            As[(kk + 2) * 68 + lr] = v.z;
            As[(kk + 3) * 68 + lr] = v.w;
        }
        // W tile (rows v0+lr), transpose into LDS (guard tail rows)
        int vr = v0 + lr;
#pragma unroll
        for (int j = 0; j < 4; j++) {
            float4 v = {0.f, 0.f, 0.f, 0.f};
            if (vr < Vn) v = *(const float4*)(W2 + (size_t)vr * 512 + k0 + lq * 16 + j * 4);
            int kk = lq * 16 + j * 4;
            Ws[(kk + 0) * 68 + lr] = v.x;
            Ws[(kk + 1) * 68 + lr] = v.y;
            Ws[(kk + 2) * 68 + lr] = v.z;
            Ws[(kk + 3) * 68 + lr] = v.w;
        }
        __syncthreads();
#pragma unroll
        for (int kk = 0; kk < 64; kk++) {
            float4 a = *(const float4*)&As[kk * 68 + ty * 4];
            float4 w = *(const float4*)&Ws[kk * 68 + tx * 4];
            acc[0][0] += a.x * w.x; acc[0][1] += a.x * w.y; acc[0][2] += a.x * w.z; acc[0][3] += a.x * w.w;
            acc[1][0] += a.y * w.x; acc[1][1] += a.y * w.y; acc[1][2] += a.y * w.z; acc[1][3] += a.y * w.w;
            acc[2][0] += a.z * w.x; acc[2][1] += a.z * w.y; acc[2][2] += a.z * w.z; acc[2][3] += a.z * w.w;
            acc[3][0] += a.w * w.x; acc[3][1] += a.w * w.y; acc[3][2] += a.w * w.z; acc[3][3] += a.w * w.w;
        }
    }
#pragma unroll
    for (int i = 0; i < 4; i++) {
        int b = ty * 4 + i;
#pragma unroll
        for (int j = 0; j < 4; j++) {
            int v = v0 + tx * 4 + j;
            if (v < Vn) out[OFF_FINAL + (size_t)b * VXn + v] = acc[i][j] + b2[v];
        }
    }
}

// K10: per-row max + sumexp over logits (in final region)
__global__ void k_vstats(const float* __restrict__ out, float* __restrict__ vmax,
                         float* __restrict__ vsum) {
    int b = blockIdx.x, tid = threadIdx.x;
    __shared__ float red[256];
    const float* lr = out + (size_t)b * VXn;
    float m = -1e30f;
    for (int v = tid; v < Vn; v += 256) m = fmaxf(m, lr[v]);
    red[tid] = m; __syncthreads();
    for (int s = 128; s > 0; s >>= 1) { if (tid < s) red[tid] = fmaxf(red[tid], red[tid + s]); __syncthreads(); }
    m = red[0]; __syncthreads();
    float s1 = 0.f;
    for (int v = tid; v < Vn; v += 256) s1 += expf(lr[v] - m);
    red[tid] = s1; __syncthreads();
    for (int s = 128; s > 0; s >>= 1) { if (tid < s) red[tid] += red[tid + s]; __syncthreads(); }
    if (tid == 0) { vmax[b] = m; vsum[b] = red[0]; }
}

// K11: final[b][v] = p_gen * softmax(logits)   for v<V, = extra_zeros for tail
__global__ void k_vfinal(const float* __restrict__ ez, float* __restrict__ out,
                         const float* __restrict__ vmax, const float* __restrict__ vsum) {
    int b = blockIdx.y;
    int v = blockIdx.x * 256 + threadIdx.x;
    if (v >= VXn) return;
    float* row = out + (size_t)b * VXn;
    if (v < Vn) {
        float pg = out[OFF_PGEN + b];
        row[v] = pg * expf(row[v] - vmax[b]) / vsum[b];
    } else {
        row[v] = ez[b * NOOVn + (v - Vn)];
    }
}

// K12: scatter-add (1-p_gen)*attn at extended-vocab indices
__global__ void k_scatter(const int* __restrict__ ive, float* __restrict__ out) {
    int g = blockIdx.x * 256 + threadIdx.x;   // 0..131071, g = t*64 + b (matches ive layout)
    int t = g >> 6, b = g & 63;
    float pg = out[OFF_PGEN + b];
    float val = (1.f - pg) * out[OFF_ATTN + b * TKn + t];
    int idx = ive[g];
    atomicAdd(&out[OFF_FINAL + (size_t)b * VXn + idx], val);
}

extern "C" void kernel_launch(void* const* d_in, const int* in_sizes, int n_in,
                              void* d_out, int out_size, void* d_ws, size_t ws_size,
                              hipStream_t stream) {
    const int*   ids   = (const int*)d_in[0];
    const float* h0    = (const float*)d_in[1];
    const float* c0    = (const float*)d_in[2];
    const float* encO  = (const float*)d_in[3];
    const float* encF  = (const float*)d_in[4];
    const float* mask  = (const float*)d_in[5];
    const float* ct1   = (const float*)d_in[6];
    const int*   ive   = (const int*)d_in[7];
    const float* cov   = (const float*)d_in[8];
    const float* ez    = (const float*)d_in[9];
    const float* Wemb  = (const float*)d_in[10];
    const float* Wctx  = (const float*)d_in[11];
    const float* bctx  = (const float*)d_in[12];
    const float* Wih   = (const float*)d_in[13];
    const float* Whh   = (const float*)d_in[14];
    const float* bih   = (const float*)d_in[15];
    const float* bhh   = (const float*)d_in[16];
    const float* Wattn = (const float*)d_in[17];
    const float* battn = (const float*)d_in[18];
    const float* vattn = (const float*)d_in[19];
    const float* Wp    = (const float*)d_in[20];
    const float* bp    = (const float*)d_in[21];
    const float* W1    = (const float*)d_in[22];
    const float* b1    = (const float*)d_in[23];
    const float* W2    = (const float*)d_in[24];
    const float* b2    = (const float*)d_in[25];
    float* out = (float*)d_out;
    float* ws  = (float*)d_ws;

    k_ctx<<<2048, 256, 0, stream>>>(ids, ct1, Wemb, Wctx, bctx, ws + WS_X);
    k_lstm<<<8192, 256, 0, stream>>>(ws + WS_X, h0, c0, Wih, Whh, bih, bhh, out);
    k_decfeat<<<16384, 256, 0, stream>>>(out, Wattn, battn, ws + WS_DECF);
    k_scores<<<32768, 256, 0, stream>>>((const float4*)encF, (const float4*)(ws + WS_DECF),
                                        (const float4*)vattn, ws + WS_SCORES);
    k_attnsm<<<64, 256, 0, stream>>>(ws + WS_SCORES, mask, cov, out);
    k_ct<<<1024, 256, 0, stream>>>((const float4*)encO, out);
    k_pgen<<<16, 256, 0, stream>>>(ws + WS_X, Wp, bp, out);
    k_out1<<<8192, 256, 0, stream>>>(out, W1, b1, ws + WS_OUT1);
    k_gemm2<<<(Vn + 63) / 64, 256, 0, stream>>>(ws + WS_OUT1, W2, b2, out);
    k_vstats<<<64, 256, 0, stream>>>(out, ws + WS_VMAX, ws + WS_VSUM);
    k_vfinal<<<dim3((VXn + 255) / 256, Bn), 256, 0, stream>>>(ez, out, ws + WS_VMAX, ws + WS_VSUM);
    k_scatter<<<512, 256, 0, stream>>>(ive, out);
}

// Round 2
// 1328.810 us; speedup vs baseline: 1.0433x; 1.0433x over previous
//
#include <hip/hip_runtime.h>
#include <cmath>

// ---- problem constants ----
constexpr int Bn = 64;
constexpr int TKn = 2048;
constexpr int Hn = 512;
constexpr int En = 128;
constexpr int Vn = 50000;
constexpr int NOOVn = 512;
constexpr int VXn = Vn + NOOVn;   // 50512

// ---- d_out layout (float offsets), flat tuple order ----
constexpr size_t OFF_FINAL = 0;                              // B x VX
constexpr size_t OFF_H     = (size_t)Bn * VXn;               // B x H
constexpr size_t OFF_C     = OFF_H + (size_t)Bn * Hn;        // B x H
constexpr size_t OFF_CT    = OFF_C + (size_t)Bn * Hn;        // B x 2H
constexpr size_t OFF_ATTN  = OFF_CT + (size_t)Bn * 2 * Hn;   // B x TK
constexpr size_t OFF_PGEN  = OFF_ATTN + (size_t)Bn * TKn;    // B
constexpr size_t OFF_COV   = OFF_PGEN + Bn;                  // B x TK

// ---- workspace layout (float offsets) ----
constexpr size_t WS_X      = 0;                               // B x E
constexpr size_t WS_DECF   = WS_X + (size_t)Bn * En;          // B x 2H
constexpr size_t WS_SCORES = WS_DECF + (size_t)Bn * 2 * Hn;   // B x TK
constexpr size_t WS_OUT1   = WS_SCORES + (size_t)Bn * TKn;    // B x H

__device__ __forceinline__ float wave_sum(float v) {
#pragma unroll
    for (int o = 32; o; o >>= 1) v += __shfl_xor(v, o, 64);
    return v;
}

// ---- fast transcendentals (v_exp_f32 / v_rcp_f32; ~1e-5 rel err, tolerance is 5.5e-2) ----
__device__ __forceinline__ float fast_exp(float x) {          // e^x
    return __builtin_amdgcn_exp2f(x * 1.4426950408889634f);
}
__device__ __forceinline__ float fast_rcp(float x) {
    return __builtin_amdgcn_rcpf(x);
}
__device__ __forceinline__ float fast_tanh(float x) {
    // 1 - 2/(1+e^{2x}); x->+inf: e=inf, rcp=0 -> 1; x->-inf: e=0 -> -1
    float e = __builtin_amdgcn_exp2f(x * 2.8853900817779268f);
    return 1.f - 2.f * __builtin_amdgcn_rcpf(1.f + e);
}
__device__ __forceinline__ float fast_sigm(float x) {
    float e = __builtin_amdgcn_exp2f(-1.4426950408889634f * x);
    return __builtin_amdgcn_rcpf(1.f + e);
}

// K1: x[b][e] = concat(c_t_1, emb) @ W_ctx.T + b_ctx   (one wave per output elem)
__global__ void k_ctx(const int* __restrict__ ids, const float* __restrict__ ct1,
                      const float* __restrict__ Wemb, const float* __restrict__ Wctx,
                      const float* __restrict__ bctx, float* __restrict__ xout) {
    int w = (blockIdx.x * 256 + threadIdx.x) >> 6;   // 0..8191
    int lane = threadIdx.x & 63;
    int b = w >> 7, e = w & 127;
    const float* wr = Wctx + (size_t)e * 1152;
    int row = ids[b];
    float acc = 0.f;
    for (int k = lane; k < 1152; k += 64) {
        float xv = (k < 1024) ? ct1[b * 1024 + k] : Wemb[(size_t)row * 128 + (k - 1024)];
        acc += xv * wr[k];
    }
    acc = wave_sum(acc);
    if (lane == 0) xout[b * 128 + e] = acc + bctx[e];
}

// K2: LSTM step -> h_dec, c_dec written straight to d_out (one wave per (b,j))
__global__ void k_lstm(const float* __restrict__ x, const float* __restrict__ h0,
                       const float* __restrict__ c0, const float* __restrict__ Wih,
                       const float* __restrict__ Whh, const float* __restrict__ bih,
                       const float* __restrict__ bhh, float* __restrict__ out) {
    int w = (blockIdx.x * 256 + threadIdx.x) >> 6;   // 0..32767
    int lane = threadIdx.x & 63;
    int b = w >> 9, j = w & 511;
    const float* xr = x + b * 128;
    const float* hr = h0 + b * 512;
    float ai = 0.f, af = 0.f, ag = 0.f, ao = 0.f;
    for (int k = lane; k < 128; k += 64) {
        float xv = xr[k];
        ai += xv * Wih[(size_t)(j       ) * 128 + k];
        af += xv * Wih[(size_t)(j +  512) * 128 + k];
        ag += xv * Wih[(size_t)(j + 1024) * 128 + k];
        ao += xv * Wih[(size_t)(j + 1536) * 128 + k];
    }
    for (int k = lane; k < 512; k += 64) {
        float hv = hr[k];
        ai += hv * Whh[(size_t)(j       ) * 512 + k];
        af += hv * Whh[(size_t)(j +  512) * 512 + k];
        ag += hv * Whh[(size_t)(j + 1024) * 512 + k];
        ao += hv * Whh[(size_t)(j + 1536) * 512 + k];
    }
    ai = wave_sum(ai); af = wave_sum(af); ag = wave_sum(ag); ao = wave_sum(ao);
    if (lane == 0) {
        ai += bih[j       ] + bhh[j       ];
        af += bih[j +  512] + bhh[j +  512];
        ag += bih[j + 1024] + bhh[j + 1024];
        ao += bih[j + 1536] + bhh[j + 1536];
        float c = fast_sigm(af) * c0[b * 512 + j] + fast_sigm(ai) * fast_tanh(ag);
        float h = fast_sigm(ao) * fast_tanh(c);
        out[OFF_H + b * 512 + j] = h;
        out[OFF_C + b * 512 + j] = c;
    }
}

// K3: dec_feature[b][n] = [h,c] @ W_attn.T + b_attn (one wave per output elem)
__global__ void k_decfeat(const float* __restrict__ out, const float* __restrict__ Wattn,
                          const float* __restrict__ battn, float* __restrict__ decF) {
    int w = (blockIdx.x * 256 + threadIdx.x) >> 6;   // 0..65535
    int lane = threadIdx.x & 63;
    int b = w >> 10, n = w & 1023;
    const float* wr = Wattn + (size_t)n * 1024;
    float acc = 0.f;
    for (int m = lane; m < 512; m += 64) acc += out[OFF_H + b * 512 + m] * wr[m];
    for (int m = lane; m < 512; m += 64) acc += out[OFF_C + b * 512 + m] * wr[512 + m];
    acc = wave_sum(acc);
    if (lane == 0) decF[b * 1024 + n] = acc + battn[n];
}

// K4: scores[b][t] = sum_n tanh(encF[b,t,n] + decF[b,n]) * v_attn[n]  (one wave per (b,t))
__global__ void k_scores(const float4* __restrict__ encF, const float4* __restrict__ decF,
                         const float4* __restrict__ vat, float* __restrict__ scores) {
    int w = (blockIdx.x * 256 + threadIdx.x) >> 6;   // 0..131071
    int lane = threadIdx.x & 63;
    int b = w >> 11, t = w & 2047;
    size_t base = ((size_t)(b * TKn + t)) * 256;     // float4 units
    float acc = 0.f;
    for (int i = lane; i < 256; i += 64) {
        float4 f = encF[base + i];
        float4 d = decF[b * 256 + i];
        float4 vv = vat[i];
        acc += fast_tanh(f.x + d.x) * vv.x + fast_tanh(f.y + d.y) * vv.y +
               fast_tanh(f.z + d.z) * vv.z + fast_tanh(f.w + d.w) * vv.w;
    }
    acc = wave_sum(acc);
    if (lane == 0) scores[b * TKn + t] = acc;
}

// K5: attention softmax (masked + renorm) -> d_out; also copy coverage, zero c_t region
__global__ void k_attnsm(const float* __restrict__ scores, const float* __restrict__ mask,
                         const float* __restrict__ cov_in, float* __restrict__ out) {
    int b = blockIdx.x, tid = threadIdx.x;
    __shared__ float red[256];
    const float* sr = scores + b * TKn;

    float m = -1e30f;
    for (int t = tid; t < TKn; t += 256) m = fmaxf(m, sr[t]);
    red[tid] = m; __syncthreads();
    for (int s = 128; s > 0; s >>= 1) { if (tid < s) red[tid] = fmaxf(red[tid], red[tid + s]); __syncthreads(); }
    m = red[0]; __syncthreads();

    float s1 = 0.f;
    for (int t = tid; t < TKn; t += 256) s1 += fast_exp(sr[t] - m);
    red[tid] = s1; __syncthreads();
    for (int s = 128; s > 0; s >>= 1) { if (tid < s) red[tid] += red[tid + s]; __syncthreads(); }
    s1 = red[0]; __syncthreads();
    float inv = fast_rcp(s1);

    float s2 = 0.f;
    for (int t = tid; t < TKn; t += 256) s2 += fast_exp(sr[t] - m) * inv * mask[b * TKn + t];
    red[tid] = s2; __syncthreads();
    for (int s = 128; s > 0; s >>= 1) { if (tid < s) red[tid] += red[tid + s]; __syncthreads(); }
    s2 = red[0];
    float invd = fast_rcp(s2);

    for (int t = tid; t < TKn; t += 256) {
        out[OFF_ATTN + b * TKn + t] = fast_exp(sr[t] - m) * inv * mask[b * TKn + t] * invd;
        out[OFF_COV  + b * TKn + t] = cov_in[b * TKn + t];
    }
    for (int n = tid; n < 1024; n += 256) out[OFF_CT + b * 1024 + n] = 0.f;
}

// K6: c_t[b][n] = sum_t attn[b][t] * encO[b][t][n]; block per (b, 128-t chunk), atomic finish
__global__ void k_ct(const float4* __restrict__ encO, float* __restrict__ out) {
    int b = blockIdx.x >> 4, ch = blockIdx.x & 15, tid = threadIdx.x;
    const float* ar = out + OFF_ATTN + b * TKn + ch * 128;
    float4 acc = {0.f, 0.f, 0.f, 0.f};
    size_t base = ((size_t)b * TKn + ch * 128) * 256 + tid;
    for (int tt = 0; tt < 128; tt++) {
        float a = ar[tt];
        float4 v = encO[base + (size_t)tt * 256];
        acc.x += a * v.x; acc.y += a * v.y; acc.z += a * v.z; acc.w += a * v.w;
    }
    float* ct = out + OFF_CT + b * 1024 + tid * 4;
    atomicAdd(ct + 0, acc.x); atomicAdd(ct + 1, acc.y);
    atomicAdd(ct + 2, acc.z); atomicAdd(ct + 3, acc.w);
}

// K7: p_gen[b] = sigmoid([c_t, h, c, x] @ W_pgen.T + b_pgen)   (one wave per b)
__global__ void k_pgen(const float* __restrict__ x, const float* __restrict__ Wp,
                       const float* __restrict__ bp, float* __restrict__ out) {
    int b = (blockIdx.x * 256 + threadIdx.x) >> 6;   // 0..63
    int lane = threadIdx.x & 63;
    float acc = 0.f;
    for (int k = lane; k < 2176; k += 64) {
        float v;
        if (k < 1024)       v = out[OFF_CT + b * 1024 + k];
        else if (k < 1536)  v = out[OFF_H + b * 512 + (k - 1024)];
        else if (k < 2048)  v = out[OFF_C + b * 512 + (k - 1536)];
        else                v = x[b * 128 + (k - 2048)];
        acc += v * Wp[k];
    }
    acc = wave_sum(acc);
    if (lane == 0) out[OFF_PGEN + b] = fast_sigm(acc + bp[0]);
}

// K8: out1[b][j] = [h_dec, c_t] @ W_out1.T + b_out1   (one wave per output elem)
__global__ void k_out1(const float* __restrict__ out, const float* __restrict__ W1,
                       const float* __restrict__ b1, float* __restrict__ o1) {
    int w = (blockIdx.x * 256 + threadIdx.x) >> 6;   // 0..32767
    int lane = threadIdx.x & 63;
    int b = w >> 9, j = w & 511;
    const float* wr = W1 + (size_t)j * 1536;
    float acc = 0.f;
    for (int k = lane; k < 512; k += 64)  acc += out[OFF_H + b * 512 + k] * wr[k];
    for (int k = lane; k < 1024; k += 64) acc += out[OFF_CT + b * 1024 + k] * wr[512 + k];
    acc = wave_sum(acc);
    if (lane == 0) o1[b * 512 + j] = acc + b1[j];
}

// K9: logits[64][50000] = out1 @ W_out2.T + b_out2, written into final-output region
// (row stride VX). Register-tiled 64x64 tile, 4x4 micro, transposed LDS tiles.
__global__ __launch_bounds__(256) void k_gemm2(const float* __restrict__ o1,
                                               const float* __restrict__ W2,
                                               const float* __restrict__ b2,
                                               float* __restrict__ out) {
    __shared__ float As[64 * 68];   // As[k][b], row stride 68 (16B-aligned, bank-shifted)
    __shared__ float Ws[64 * 68];   // Ws[k][v]
    int tid = threadIdx.x;
    int v0 = blockIdx.x * 64;
    int tx = tid & 15, ty = tid >> 4;
    int lr = tid >> 2;   // loaded row 0..63
    int lq = tid & 3;    // k-slice quarter
    float acc[4][4] = {};

    for (int k0 = 0; k0 < 512; k0 += 64) {
        __syncthreads();
        const float4* arow = (const float4*)(o1 + (size_t)lr * 512 + k0 + lq * 16);
#pragma unroll
        for (int j = 0; j < 4; j++) {
            float4 v = arow[j];
            int kk = lq * 16 + j * 4;
            As[(kk + 0) * 68 + lr] = v.x;
            As[(kk + 1) * 68 + lr] = v.y;
            As[(kk + 2) * 68 + lr] = v.z;
            As[(kk + 3) * 68 + lr] = v.w;
        }
        int vr = v0 + lr;
#pragma unroll
        for (int j = 0; j < 4; j++) {
            float4 v = {0.f, 0.f, 0.f, 0.f};
            if (vr < Vn) v = *(const float4*)(W2 + (size_t)vr * 512 + k0 + lq * 16 + j * 4);
            int kk = lq * 16 + j * 4;
            Ws[(kk + 0) * 68 + lr] = v.x;
            Ws[(kk + 1) * 68 + lr] = v.y;
            Ws[(kk + 2) * 68 + lr] = v.z;
            Ws[(kk + 3) * 68 + lr] = v.w;
        }
        __syncthreads();
#pragma unroll
        for (int kk = 0; kk < 64; kk++) {
            float4 a = *(const float4*)&As[kk * 68 + ty * 4];
            float4 w = *(const float4*)&Ws[kk * 68 + tx * 4];
            acc[0][0] += a.x * w.x; acc[0][1] += a.x * w.y; acc[0][2] += a.x * w.z; acc[0][3] += a.x * w.w;
            acc[1][0] += a.y * w.x; acc[1][1] += a.y * w.y; acc[1][2] += a.y * w.z; acc[1][3] += a.y * w.w;
            acc[2][0] += a.z * w.x; acc[2][1] += a.z * w.y; acc[2][2] += a.z * w.z; acc[2][3] += a.z * w.w;
            acc[3][0] += a.w * w.x; acc[3][1] += a.w * w.y; acc[3][2] += a.w * w.z; acc[3][3] += a.w * w.w;
        }
    }
#pragma unroll
    for (int i = 0; i < 4; i++) {
        int b = ty * 4 + i;
#pragma unroll
        for (int j = 0; j < 4; j++) {
            int v = v0 + tx * 4 + j;
            if (v < Vn) out[OFF_FINAL + (size_t)b * VXn + v] = acc[i][j] + b2[v];
        }
    }
}

// K10 (fused vstats+vfinal): softmax over logits row (in place) * p_gen, + extra_zeros tail.
// One block per row; passes 2-3 hit L2 (200 KB/row stays in the XCD's L2).
__global__ __launch_bounds__(1024) void k_vsoft(const float* __restrict__ ez,
                                                float* __restrict__ out) {
    int b = blockIdx.x, tid = threadIdx.x;
    __shared__ float red[1024];
    float* row = out + (size_t)b * VXn;

    float m = -1e30f;
    for (int v = tid; v < Vn; v += 1024) m = fmaxf(m, row[v]);
    red[tid] = m; __syncthreads();
    for (int s = 512; s > 0; s >>= 1) { if (tid < s) red[tid] = fmaxf(red[tid], red[tid + s]); __syncthreads(); }
    m = red[0]; __syncthreads();

    float s1 = 0.f;
    for (int v = tid; v < Vn; v += 1024) s1 += fast_exp(row[v] - m);
    red[tid] = s1; __syncthreads();
    for (int s = 512; s > 0; s >>= 1) { if (tid < s) red[tid] += red[tid + s]; __syncthreads(); }
    float pg = out[OFF_PGEN + b];
    float scale = pg * fast_rcp(red[0]);

    for (int v = tid; v < Vn; v += 1024) row[v] = fast_exp(row[v] - m) * scale;
    for (int v = Vn + tid; v < VXn; v += 1024) row[v] = ez[b * NOOVn + (v - Vn)];
}

// K11: scatter-add (1-p_gen)*attn at extended-vocab indices
__global__ void k_scatter(const int* __restrict__ ive, float* __restrict__ out) {
    int g = blockIdx.x * 256 + threadIdx.x;   // 0..131071, g = t*64 + b (matches ive layout)
    int t = g >> 6, b = g & 63;
    float pg = out[OFF_PGEN + b];
    float val = (1.f - pg) * out[OFF_ATTN + b * TKn + t];
    int idx = ive[g];
    atomicAdd(&out[OFF_FINAL + (size_t)b * VXn + idx], val);
}

extern "C" void kernel_launch(void* const* d_in, const int* in_sizes, int n_in,
                              void* d_out, int out_size, void* d_ws, size_t ws_size,
                              hipStream_t stream) {
    const int*   ids   = (const int*)d_in[0];
    const float* h0    = (const float*)d_in[1];
    const float* c0    = (const float*)d_in[2];
    const float* encO  = (const float*)d_in[3];
    const float* encF  = (const float*)d_in[4];
    const float* mask  = (const float*)d_in[5];
    const float* ct1   = (const float*)d_in[6];
    const int*   ive   = (const int*)d_in[7];
    const float* cov   = (const float*)d_in[8];
    const float* ez    = (const float*)d_in[9];
    const float* Wemb  = (const float*)d_in[10];
    const float* Wctx  = (const float*)d_in[11];
    const float* bctx  = (const float*)d_in[12];
    const float* Wih   = (const float*)d_in[13];
    const float* Whh   = (const float*)d_in[14];
    const float* bih   = (const float*)d_in[15];
    const float* bhh   = (const float*)d_in[16];
    const float* Wattn = (const float*)d_in[17];
    const float* battn = (const float*)d_in[18];
    const float* vattn = (const float*)d_in[19];
    const float* Wp    = (const float*)d_in[20];
    const float* bp    = (const float*)d_in[21];
    const float* W1    = (const float*)d_in[22];
    const float* b1    = (const float*)d_in[23];
    const float* W2    = (const float*)d_in[24];
    const float* b2    = (const float*)d_in[25];
    float* out = (float*)d_out;
    float* ws  = (float*)d_ws;

    k_ctx<<<2048, 256, 0, stream>>>(ids, ct1, Wemb, Wctx, bctx, ws + WS_X);
    k_lstm<<<8192, 256, 0, stream>>>(ws + WS_X, h0, c0, Wih, Whh, bih, bhh, out);
    k_decfeat<<<16384, 256, 0, stream>>>(out, Wattn, battn, ws + WS_DECF);
    k_scores<<<32768, 256, 0, stream>>>((const float4*)encF, (const float4*)(ws + WS_DECF),
                                        (const float4*)vattn, ws + WS_SCORES);
    k_attnsm<<<64, 256, 0, stream>>>(ws + WS_SCORES, mask, cov, out);
    k_ct<<<1024, 256, 0, stream>>>((const float4*)encO, out);
    k_pgen<<<16, 256, 0, stream>>>(ws + WS_X, Wp, bp, out);
    k_out1<<<8192, 256, 0, stream>>>(out, W1, b1, ws + WS_OUT1);
    k_gemm2<<<(Vn + 63) / 64, 256, 0, stream>>>(ws + WS_OUT1, W2, b2, out);
    k_vsoft<<<64, 1024, 0, stream>>>(ez, out);
    k_scatter<<<512, 256, 0, stream>>>(ive, out);
}